// Round 6
// baseline (137.937 us; speedup 1.0000x reference)
//
#include <hip/hip_runtime.h>

// HardPartPyramidPooling: x(16,256,32,16,11) fp32, labels(16,32,176) int,
// out(16,256,32,16) fp32.  out[n][c][s][p] = sum/cnt + max (0 if cnt==0),
// max floored at NEG_FILL=-100 (reference init).
//
// R11: TWO-KERNEL SPLIT. R7-R10 nulls proved the ~25us slice is invariant
// to barrier drains, DRAM alignment, gather instr count, and inter-wave
// sync. Remaining shared trait: every block redid label bucketing as a
// serial chain, and x segments were 45-KB-strided. Now:
//  k1 (512 blocks): bucket each ns row ONCE -> d_ws: posmap u32[512][44]
//     (u8 sorted-position per hw) + packed pk u32[512][16] (base<<8|cnt).
//  k2 (4096 blocks = one (n,c) x-row each, 22.5 KB CONTIGUOUS):
//     - each thread loads its OWN 6 posmap words + 2 pk words + 6 x
//       float4s (no LDS metadata staging: scatter needs pm word j at the
//       thread's own linear j; gather needs pk at the thread's own idx).
//     - scatter-sort into tile[32][PITCH], ONE barrier, contiguous
//       float4 gather, 2 coalesced output stores (2 KB/block).
//     - no atomics, no scan, no label reads, LDS = 23 KB (7 blk/CU).
//  - ws layout: pm[0..90112) pk[90112..122880). Fallback to proven R7
//    single-kernel if ws_size < 122880.

constexpr int C   = 256;
constexpr int S   = 32;
constexpr int HW  = 176;        // 16*11
constexpr int P   = 16;
constexpr int ROW = S * HW;     // 5632 floats per (n,c)
constexpr int PITCH = 180;      // floats; %4==0 (b128 align), /4 odd (bank spread)
constexpr float NEG_FILL = -100.0f;

__device__ __forceinline__ void barrier_lgkm() {
    asm volatile("s_waitcnt lgkmcnt(0)\n\ts_barrier" ::: "memory");
}

// ---------------- kernel 1: bucket each ns row once ----------------------
__global__ __launch_bounds__(256) void bucket_kernel(
    const int* __restrict__ labels,
    unsigned*  __restrict__ pm,     // [512][44] u32 (u8 posmap words)
    unsigned*  __restrict__ pk)     // [512][16]  base<<8 | cnt
{
    __shared__ int cnt[P];
    __shared__ int base[P];
    __shared__ __align__(4) unsigned char posmap[HW];

    const int tid = threadIdx.x;
    const int ns  = blockIdx.x;

    int lab = 0, r = 0;
    if (tid < HW) lab = labels[(size_t)ns * HW + tid];
    if (tid < P)  cnt[tid] = 0;
    __syncthreads();
    if (tid < HW) r = atomicAdd(&cnt[lab], 1);
    __syncthreads();
    if (tid < P) {
        int acc = 0;
        for (int q = 0; q < tid; ++q) acc += cnt[q];
        base[tid] = acc;
    }
    __syncthreads();
    if (tid < HW) posmap[tid] = (unsigned char)(base[lab] + r);
    __syncthreads();
    if (tid < HW / 4) pm[(size_t)ns * 44 + tid] = ((const unsigned*)posmap)[tid];
    if (tid < P)      pk[(size_t)ns * P + tid] =
                          ((unsigned)base[tid] << 8) | (unsigned)cnt[tid];
}

// ---------------- kernel 2: stream one (n,c) row per block ---------------
__global__ __launch_bounds__(256) void hpp_main(
    const float*    __restrict__ x,
    const unsigned* __restrict__ pm,
    const unsigned* __restrict__ pk,
    float*          __restrict__ out)
{
    __shared__ float tile[S * PITCH];            // 32*180*4 = 23040 B

    const int tid = threadIdx.x;
    const int blk = blockIdx.x;                  // n*256 + c (x-sequential)
    const int n   = blk >> 8, c = blk & 255;

    // ---- metadata loads FIRST (small, L2-hot): thread's own words -------
    const unsigned* pmn = pm + (size_t)n * S * 44;   // 1408 words
    const unsigned* pkn = pk + (size_t)n * S * P;    // 512 words
    unsigned w0 = pmn[tid];
    unsigned w1 = pmn[tid + 256];
    unsigned w2 = pmn[tid + 512];
    unsigned w3 = pmn[tid + 768];
    unsigned w4 = pmn[tid + 1024];
    const bool has5 = (tid < 1408 - 1280);           // tid < 128
    unsigned w5 = 0; if (has5) w5 = pmn[tid + 1280];
    unsigned q0 = pkn[tid];
    unsigned q1 = pkn[tid + 256];

    // ---- x row: 1408 float4, fully contiguous (22528 B) -----------------
    const float4* xr = (const float4*)(x + (size_t)(n * C + c) * ROW);
    float4 v0 = xr[tid];
    float4 v1 = xr[tid + 256];
    float4 v2 = xr[tid + 512];
    float4 v3 = xr[tid + 768];
    float4 v4 = xr[tid + 1024];
    float4 v5 = make_float4(0.f, 0.f, 0.f, 0.f);
    if (has5) v5 = xr[tid + 1280];

    // ---- scatter-sort: float4 j covers row s=j/44, word jj=j-44s; pm
    //      word j holds the 4 sorted positions ----------------------------
    {
#define SCAT(J, W, V)                                                      \
        {                                                                  \
            const int s_ = (J) / 44;                                       \
            float* t_ = &tile[s_ * PITCH];                                 \
            t_[(W) & 0xFF] = (V).x;  t_[((W) >> 8) & 0xFF] = (V).y;        \
            t_[((W) >> 16) & 0xFF] = (V).z;  t_[(W) >> 24] = (V).w;        \
        }
        SCAT(tid,        w0, v0)
        SCAT(tid + 256,  w1, v1)
        SCAT(tid + 512,  w2, v2)
        SCAT(tid + 768,  w3, v3)
        SCAT(tid + 1024, w4, v4)
        if (has5) SCAT(tid + 1280, w5, v5)
#undef SCAT
    }
    barrier_lgkm();

    // ---- contiguous gather: idx = tid, tid+256; s = idx>>4, p = idx&15 --
    float res[2];
    #pragma unroll
    for (int o = 0; o < 2; ++o) {
        const unsigned w = o ? q1 : q0;
        const int k   = (int)(w & 0xFF);
        int off       = (int)(w >> 8);
        const int idx = tid + o * 256;
        const float* tc = &tile[(idx >> 4) * PITCH];

        float s0 = 0.f, s1 = 0.f, m0 = NEG_FILL, m1 = NEG_FILL;
        int rem = k;
        int h = (4 - (off & 3)) & 3; if (h > rem) h = rem;
        if (h > 0) { float a = tc[off];     s0 += a; m0 = fmaxf(m0, a); }
        if (h > 1) { float a = tc[off + 1]; s1 += a; m1 = fmaxf(m1, a); }
        if (h > 2) { float a = tc[off + 2]; s0 += a; m0 = fmaxf(m0, a); }
        off += h; rem -= h;
        int n4 = rem >> 2;
        for (int i = 0; i < n4; ++i) {
            float4 q = *(const float4*)&tc[off];
            s0 += q.x; m0 = fmaxf(m0, q.x);
            s1 += q.y; m1 = fmaxf(m1, q.y);
            s0 += q.z; m0 = fmaxf(m0, q.z);
            s1 += q.w; m1 = fmaxf(m1, q.w);
            off += 4;
        }
        rem &= 3;
        if (rem > 0) { float a = tc[off];     s0 += a; m0 = fmaxf(m0, a); }
        if (rem > 1) { float a = tc[off + 1]; s1 += a; m1 = fmaxf(m1, a); }
        if (rem > 2) { float a = tc[off + 2]; s0 += a; m0 = fmaxf(m0, a); }

        res[o] = (k > 0) ? (s0 + s1) / (float)k + fmaxf(m0, m1) : 0.f;
    }

    // ---- out: block owns out[n][c][*][*] = 512 floats contiguous --------
    float* op = out + (size_t)(n * C + c) * (S * P);
    op[tid]       = res[0];
    op[tid + 256] = res[1];
}

// ---------------- fallback (proven R7): single fused kernel --------------
constexpr int GC_F  = 16;
constexpr int PIT_F = 178;
constexpr int BCAP  = 64;

__global__ __launch_bounds__(256) void hpp_fallback(
    const float* __restrict__ x,
    const int*   __restrict__ labels,
    float*       __restrict__ out)
{
    __shared__ float         tile[GC_F * PIT_F];
    __shared__ unsigned char perm[P * BCAP];
    __shared__ int           cnt[P];

    const int tid = threadIdx.x;
    const int blk = blockIdx.x;
    const int ns  = blk >> 4, cg = blk & 15;
    const int n   = ns >> 5,  s  = ns & 31;

    const int* ln = labels + (size_t)ns * HW;
    int lab = 0;
    if (tid < HW) lab = ln[tid];

    const float* xb = x + (size_t)(n * C + cg * GC_F) * ROW + s * HW;
    const int f0 = tid, f1 = tid + 256, f2 = tid + 512;
    const int r0 = f0 / 44, j0 = f0 - r0 * 44;
    const int r1 = f1 / 44, j1 = f1 - r1 * 44;
    const int r2 = f2 / 44, j2 = f2 - r2 * 44;
    float4 v0 = *(const float4*)(xb + (size_t)r0 * ROW + j0 * 4);
    float4 v1 = *(const float4*)(xb + (size_t)r1 * ROW + j1 * 4);
    float4 v2 = make_float4(0.f, 0.f, 0.f, 0.f);
    const bool has2 = (f2 < GC_F * 44);
    if (has2) v2 = *(const float4*)(xb + (size_t)r2 * ROW + j2 * 4);

    ((unsigned*)perm)[tid] = 0u;
    if (tid < P) cnt[tid] = 0;
    barrier_lgkm();
    if (tid < HW) {
        int r = atomicAdd(&cnt[lab], 1);
        if (r < BCAP) perm[(lab << 6) + r] = (unsigned char)tid;
    }
    barrier_lgkm();
    {
        float2* t0 = (float2*)&tile[r0 * PIT_F + j0 * 4];
        t0[0] = make_float2(v0.x, v0.y); t0[1] = make_float2(v0.z, v0.w);
        float2* t1 = (float2*)&tile[r1 * PIT_F + j1 * 4];
        t1[0] = make_float2(v1.x, v1.y); t1[1] = make_float2(v1.z, v1.w);
        if (has2) {
            float2* t2 = (float2*)&tile[r2 * PIT_F + j2 * 4];
            t2[0] = make_float2(v2.x, v2.y); t2[1] = make_float2(v2.z, v2.w);
        }
    }
    barrier_lgkm();

    const int p = tid >> 4, c = tid & 15;
    const int k = min(cnt[p], BCAP);
    const unsigned char* pp = &perm[p << 6];
    const float*         tc = &tile[c * PIT_F];

    float s0 = 0.f, s1 = 0.f, m0 = NEG_FILL, m1 = NEG_FILL;
    const int kf = k & ~3;
    for (int j = 0; j < kf; j += 4) {
        unsigned u = *(const unsigned*)&pp[j];
        float a0 = tc[u & 0xFF];
        float a1 = tc[(u >> 8) & 0xFF];
        float a2 = tc[(u >> 16) & 0xFF];
        float a3 = tc[u >> 24];
        s0 += a0; m0 = fmaxf(m0, a0);
        s1 += a1; m1 = fmaxf(m1, a1);
        s0 += a2; m0 = fmaxf(m0, a2);
        s1 += a3; m1 = fmaxf(m1, a3);
    }
    if (kf < k) {
        unsigned u = *(const unsigned*)&pp[kf];
        float a0 = tc[u & 0xFF];
        float a1 = tc[(u >> 8) & 0xFF];
        float a2 = tc[(u >> 16) & 0xFF];
        s0 += a0; m0 = fmaxf(m0, a0);
        if (kf + 1 < k) { s1 += a1; m1 = fmaxf(m1, a1); }
        if (kf + 2 < k) { s0 += a2; m0 = fmaxf(m0, a2); }
    }

    float res = (k > 0) ? (s0 + s1) / (float)k + fmaxf(m0, m1) : 0.f;
    out[((size_t)(n * C + cg * GC_F + c) * S + s) * P + p] = res;
}

extern "C" void kernel_launch(void* const* d_in, const int* in_sizes, int n_in,
                              void* d_out, int out_size, void* d_ws, size_t ws_size,
                              hipStream_t stream) {
    const float* x      = (const float*)d_in[0];
    const int*   labels = (const int*)d_in[1];
    float*       out    = (float*)d_out;

    const int ns_total = in_sizes[1] / HW;                 // 512
    const size_t pm_bytes = (size_t)ns_total * 44 * 4;     // 90112
    const size_t pk_bytes = (size_t)ns_total * P * 4;      // 32768

    if (ws_size >= pm_bytes + pk_bytes) {
        unsigned* pm = (unsigned*)d_ws;
        unsigned* pk = (unsigned*)((char*)d_ws + pm_bytes);
        bucket_kernel<<<ns_total, 256, 0, stream>>>(labels, pm, pk);
        const int nblk = (ns_total / S) * C;               // 16*256 = 4096
        hpp_main<<<nblk, 256, 0, stream>>>(x, pm, pk, out);
    } else {
        hpp_fallback<<<ns_total * (C / GC_F), 256, 0, stream>>>(x, labels, out);
    }
}